// Round 2
// baseline (2014.220 us; speedup 1.0000x reference)
//
#include <hip/hip_runtime.h>
#include <math.h>

// Problem constants (from reference): B=4, L=4096, D=1024
#define B_SZ 4
#define L_SZ 4096
#define D_SZ 1024
#define M_SZ (B_SZ * L_SZ)      // 16384 tokens
#define NBINS 513               // rfft bins for D=1024
#define CCH   (2 * NBINS)       // 1026 float channels per token (interleaved re,im)
#define TCH 32                  // cumsum chunks over L
#define TLEN (L_SZ / TCH)       // 128 timesteps per chunk

// ---------------------------------------------------------------------------
// In-LDS 1024-point complex FFT, 256 threads. sign=-1 forward, +1 inverse
// (inverse does NOT scale by 1/N; caller applies it).
// Caller must __syncthreads() before calling (data visible in LDS).
// ---------------------------------------------------------------------------
__device__ inline void fft1024(float* re, float* im, int tid, float sign) {
    // bit-reverse permutation (10 bits)
    for (int i = tid; i < 1024; i += 256) {
        int r = __brev(i) >> 22;
        if (i < r) {
            float tr = re[i]; re[i] = re[r]; re[r] = tr;
            float ti = im[i]; im[i] = im[r]; im[r] = ti;
        }
    }
    __syncthreads();
    for (int s = 0; s < 10; s++) {
        const int half = 1 << s;
        const float ang_scale = sign * 3.14159265358979323846f / (float)half;
        #pragma unroll
        for (int jj = 0; jj < 2; jj++) {
            int j = tid + jj * 256;          // j in [0, 512)
            int pos = j & (half - 1);
            int i1 = ((j >> s) << (s + 1)) + pos;
            int i2 = i1 + half;
            float ang = ang_scale * (float)pos;
            float sn, cs;
            __sincosf(ang, &sn, &cs);
            float xr = re[i2], xi = im[i2];
            float tr = xr * cs - xi * sn;
            float ti = xr * sn + xi * cs;
            float ur = re[i1], ui = im[i1];
            re[i1] = ur + tr; im[i1] = ui + ti;
            re[i2] = ur - tr; im[i2] = ui - ti;
        }
        __syncthreads();
    }
}

// ---------------------------------------------------------------------------
// GEMM: C[m,n] = sum_k A[m,k]*W[n,k] + bias[n] (+ resid[m,n] if resid != null)
// A:[M,K] row-major, W:[N,K] row-major (i.e. torch Linear weight).
// Tiles: 64x64, BK=16, 256 threads, 4x4 outputs/thread. fp32 vector ALU.
// ---------------------------------------------------------------------------
#define BM 64
#define BN 64
#define BK 16
__global__ __launch_bounds__(256) void gemm_bias(
        const float* __restrict__ A, const float* __restrict__ W,
        const float* __restrict__ bias, const float* __restrict__ resid,
        float* __restrict__ C, int M, int N, int K) {
    __shared__ __align__(16) float As[BK][BM + 4];
    __shared__ __align__(16) float Ws[BK][BN + 4];
    const int bm = blockIdx.y * BM;
    const int bn = blockIdx.x * BN;
    const int tid = threadIdx.x;
    const int tx = tid & 15;         // 0..15 -> 4 cols each
    const int ty = tid >> 4;         // 0..15 -> 4 rows each
    const int ar = tid >> 2;         // 0..63 (tile row for loads)
    const int ac = (tid & 3) * 4;    // 0,4,8,12 (k-offset for float4 load)

    float acc[4][4];
    #pragma unroll
    for (int i = 0; i < 4; i++)
        #pragma unroll
        for (int j = 0; j < 4; j++) acc[i][j] = 0.0f;

    for (int k0 = 0; k0 < K; k0 += BK) {
        float4 av = *(const float4*)&A[(size_t)(bm + ar) * K + k0 + ac];
        float4 wv = *(const float4*)&W[(size_t)(bn + ar) * K + k0 + ac];
        As[ac + 0][ar] = av.x; As[ac + 1][ar] = av.y;
        As[ac + 2][ar] = av.z; As[ac + 3][ar] = av.w;
        Ws[ac + 0][ar] = wv.x; Ws[ac + 1][ar] = wv.y;
        Ws[ac + 2][ar] = wv.z; Ws[ac + 3][ar] = wv.w;
        __syncthreads();
        #pragma unroll
        for (int kk = 0; kk < BK; kk++) {
            float4 a4 = *(const float4*)&As[kk][ty * 4];
            float4 b4 = *(const float4*)&Ws[kk][tx * 4];
            float ai[4] = {a4.x, a4.y, a4.z, a4.w};
            float bj[4] = {b4.x, b4.y, b4.z, b4.w};
            #pragma unroll
            for (int i = 0; i < 4; i++)
                #pragma unroll
                for (int j = 0; j < 4; j++)
                    acc[i][j] += ai[i] * bj[j];
        }
        __syncthreads();
    }

    float4 b4 = *(const float4*)&bias[bn + tx * 4];
    #pragma unroll
    for (int i = 0; i < 4; i++) {
        size_t row = (size_t)(bm + ty * 4 + i);
        size_t off = row * N + bn + tx * 4;
        float4 v;
        v.x = acc[i][0] + b4.x; v.y = acc[i][1] + b4.y;
        v.z = acc[i][2] + b4.z; v.w = acc[i][3] + b4.w;
        if (resid) {
            float4 r4 = *(const float4*)&resid[off];
            v.x += r4.x; v.y += r4.y; v.z += r4.z; v.w += r4.w;
        }
        *(float4*)&C[off] = v;
    }
}

// ---------------------------------------------------------------------------
// Per-token: normalize keys, FFT keys & values, write P = Kf*Vf only.
// P layout: [token][bin] interleaved (re,im), CCH floats per token.
// (Kf is NOT stored; unbind recomputes it from Kraw — saves 67 MB of ws.)
// ---------------------------------------------------------------------------
__global__ __launch_bounds__(256) void bind_fft_kernel(
        const float* __restrict__ Kraw, const float* __restrict__ V,
        float* __restrict__ P) {
    __shared__ float kre[1024], kim[1024], vre[1024], vim[1024];
    __shared__ float red[256];
    const int token = blockIdx.x;
    const int tid = threadIdx.x;

    const float* krow = Kraw + (size_t)token * D_SZ;
    float ss = 0.0f;
    for (int i = tid; i < 1024; i += 256) {
        float v = krow[i];
        kre[i] = v; kim[i] = 0.0f;
        ss += v * v;
    }
    red[tid] = ss;
    __syncthreads();
    for (int s = 128; s > 0; s >>= 1) {
        if (tid < s) red[tid] += red[tid + s];
        __syncthreads();
    }
    const float scale = 1.0f / fmaxf(sqrtf(red[0]), 1e-12f);
    __syncthreads();
    for (int i = tid; i < 1024; i += 256) kre[i] *= scale;

    const float* vrow = V + (size_t)token * D_SZ;
    for (int i = tid; i < 1024; i += 256) { vre[i] = vrow[i]; vim[i] = 0.0f; }
    __syncthreads();

    fft1024(kre, kim, tid, -1.0f);
    fft1024(vre, vim, tid, -1.0f);

    float2* Po = (float2*)(P + (size_t)token * CCH);
    for (int bin = tid; bin < NBINS; bin += 256) {
        float kr = kre[bin], ki = kim[bin];
        float vr = vre[bin], vi = vim[bin];
        Po[bin] = make_float2(kr * vr - ki * vi, kr * vi + ki * vr);
    }
}

// ---------------------------------------------------------------------------
// Cumsum over t (chunked two-pass). Channels c in [0,CCH) per batch b.
// Pass 1: in-place local cumsum within each t-chunk + write chunk totals.
// ---------------------------------------------------------------------------
__global__ __launch_bounds__(256) void cumsum_local(
        float* __restrict__ S, float* __restrict__ totals) {
    const int c = blockIdx.x * 256 + threadIdx.x;
    if (c >= CCH) return;
    const int chunk = blockIdx.y;
    const int b = blockIdx.z;
    size_t p = ((size_t)b * L_SZ + (size_t)chunk * TLEN) * CCH + c;
    float acc = 0.0f;
    #pragma unroll 4
    for (int t = 0; t < TLEN; t++) {
        acc += S[p];
        S[p] = acc;
        p += CCH;
    }
    totals[((size_t)b * TCH + chunk) * CCH + c] = acc;
}

// Pass 2: add exclusive prefix of chunk totals to each chunk.
__global__ __launch_bounds__(256) void cumsum_add(
        float* __restrict__ S, const float* __restrict__ totals) {
    const int c = blockIdx.x * 256 + threadIdx.x;
    if (c >= CCH) return;
    const int chunk = blockIdx.y;
    if (chunk == 0) return;
    const int b = blockIdx.z;
    float off = 0.0f;
    for (int j = 0; j < chunk; j++)
        off += totals[((size_t)b * TCH + j) * CCH + c];
    size_t p = ((size_t)b * L_SZ + (size_t)chunk * TLEN) * CCH + c;
    #pragma unroll 4
    for (int t = 0; t < TLEN; t++) {
        S[p] += off;
        p += CCH;
    }
}

// ---------------------------------------------------------------------------
// Per-token: recompute Kf from raw keys (norm + FFT), Rf = S*conj(Kf),
// Hermitian extend, inverse FFT, /sqrt(t+1), LayerNorm(eps=1e-5) -> RLN.
// ---------------------------------------------------------------------------
__global__ __launch_bounds__(256) void unbind_ln_kernel(
        const float* __restrict__ S, const float* __restrict__ Kraw,
        const float* __restrict__ ln_g, const float* __restrict__ ln_b,
        float* __restrict__ RLN) {
    __shared__ float kre[1024], kim[1024];
    __shared__ float re[1024], im[1024];
    __shared__ float red1[256], red2[256];
    const int token = blockIdx.x;
    const int tid = threadIdx.x;
    const int t = token & (L_SZ - 1);

    // recompute normalized key FFT
    const float* krow = Kraw + (size_t)token * D_SZ;
    float ss = 0.0f;
    for (int i = tid; i < 1024; i += 256) {
        float v = krow[i];
        kre[i] = v; kim[i] = 0.0f;
        ss += v * v;
    }
    red1[tid] = ss;
    __syncthreads();
    for (int s = 128; s > 0; s >>= 1) {
        if (tid < s) red1[tid] += red1[tid + s];
        __syncthreads();
    }
    const float scale = 1.0f / fmaxf(sqrtf(red1[0]), 1e-12f);
    __syncthreads();
    for (int i = tid; i < 1024; i += 256) kre[i] *= scale;
    __syncthreads();
    fft1024(kre, kim, tid, -1.0f);

    // Rf = S * conj(Kf) on bins 0..512
    const float2* Srow = (const float2*)(S + (size_t)token * CCH);
    for (int bin = tid; bin < NBINS; bin += 256) {
        float2 s2 = Srow[bin];
        float kr = kre[bin], ki = kim[bin];
        re[bin] = s2.x * kr + s2.y * ki;
        im[bin] = s2.y * kr - s2.x * ki;
    }
    __syncthreads();
    // Hermitian extension to bins 513..1023
    for (int n = 513 + tid; n < 1024; n += 256) {
        re[n] = re[1024 - n];
        im[n] = -im[1024 - n];
    }
    __syncthreads();

    fft1024(re, im, tid, +1.0f);

    const float posscale = (1.0f / 1024.0f) * rsqrtf((float)(t + 1));
    float rv[4];
    float sum = 0.0f, sumsq = 0.0f;
    #pragma unroll
    for (int i = 0; i < 4; i++) {
        int d = tid + i * 256;
        float v = re[d] * posscale;
        rv[i] = v;
        sum += v;
        sumsq += v * v;
    }
    red1[tid] = sum; red2[tid] = sumsq;
    __syncthreads();
    for (int s = 128; s > 0; s >>= 1) {
        if (tid < s) { red1[tid] += red1[tid + s]; red2[tid] += red2[tid + s]; }
        __syncthreads();
    }
    const float mu = red1[0] * (1.0f / 1024.0f);
    const float var = red2[0] * (1.0f / 1024.0f) - mu * mu;
    const float rstd = rsqrtf(var + 1e-5f);

    float* out = RLN + (size_t)token * D_SZ;
    #pragma unroll
    for (int i = 0; i < 4; i++) {
        int d = tid + i * 256;
        out[d] = (rv[i] - mu) * rstd * ln_g[d] + ln_b[d];
    }
}

// ---------------------------------------------------------------------------
// Workspace layout (fp32):
//   Kraw   : M*D      = 64.0 MB   (raw keys; read again by unbind)
//   V      : M*D      = 64.0 MB   (values; reused as RLN after bind)
//   P      : M*CCH    = 67.2 MB   (bound spectra -> cumsum in place)
//   totals : B*TCH*CCH =  0.5 MB
//   total ~= 202 MB  (must stay under ws_size; Kf buffer eliminated)
// ---------------------------------------------------------------------------
extern "C" void kernel_launch(void* const* d_in, const int* in_sizes, int n_in,
                              void* d_out, int out_size, void* d_ws, size_t ws_size,
                              hipStream_t stream) {
    (void)in_sizes; (void)n_in; (void)out_size; (void)ws_size;
    const float* x    = (const float*)d_in[0];
    const float* Wk   = (const float*)d_in[1];
    const float* bk   = (const float*)d_in[2];
    const float* Wv   = (const float*)d_in[3];
    const float* bv   = (const float*)d_in[4];
    const float* ln_g = (const float*)d_in[5];
    const float* ln_b = (const float*)d_in[6];
    const float* Wo   = (const float*)d_in[7];
    const float* bo   = (const float*)d_in[8];
    float* out = (float*)d_out;

    float* ws     = (float*)d_ws;
    float* Kraw   = ws;                               // M*D
    float* V      = Kraw + (size_t)M_SZ * D_SZ;       // M*D; reused as RLN
    float* P      = V    + (size_t)M_SZ * D_SZ;       // M*CCH (becomes S in place)
    float* totals = P    + (size_t)M_SZ * CCH;        // B*TCH*CCH

    dim3 ggrid(D_SZ / BN, M_SZ / BM);                 // (16, 256)
    gemm_bias<<<ggrid, 256, 0, stream>>>(x, Wk, bk, nullptr, Kraw, M_SZ, D_SZ, D_SZ);
    gemm_bias<<<ggrid, 256, 0, stream>>>(x, Wv, bv, nullptr, V,    M_SZ, D_SZ, D_SZ);

    bind_fft_kernel<<<M_SZ, 256, 0, stream>>>(Kraw, V, P);

    dim3 cgrid((CCH + 255) / 256, TCH, B_SZ);         // (5, 32, 4)
    cumsum_local<<<cgrid, 256, 0, stream>>>(P, totals);
    cumsum_add<<<cgrid, 256, 0, stream>>>(P, totals);

    // RLN written into V (V is dead after bind_fft)
    unbind_ln_kernel<<<M_SZ, 256, 0, stream>>>(P, Kraw, ln_g, ln_b, V);

    gemm_bias<<<ggrid, 256, 0, stream>>>(V, Wo, bo, x, out, M_SZ, D_SZ, D_SZ);
}

// Round 3
// 839.674 us; speedup vs baseline: 2.3988x; 2.3988x over previous
//
#include <hip/hip_runtime.h>
#include <math.h>

// Problem constants (from reference): B=4, L=4096, D=1024
#define B_SZ 4
#define L_SZ 4096
#define D_SZ 1024
#define M_SZ (B_SZ * L_SZ)      // 16384 tokens
#define NBINS 513               // rfft bins for D=1024
#define CCH   (2 * NBINS)       // 1026 float channels per token (interleaved re,im)
#define TCH 32                  // cumsum chunks over L
#define TLEN (L_SZ / TCH)       // 128 timesteps per chunk

typedef short bf16x8 __attribute__((ext_vector_type(8)));
typedef float f32x4  __attribute__((ext_vector_type(4)));
typedef unsigned short us8 __attribute__((ext_vector_type(8)));

// round-to-nearest-even f32 -> bf16
__device__ inline unsigned short f2bf(float f) {
    unsigned int u = __float_as_uint(f);
    u += 0x7fffu + ((u >> 16) & 1u);
    return (unsigned short)(u >> 16);
}

// ---------------------------------------------------------------------------
// f32 -> bf16 cast, 8 elements/thread
// ---------------------------------------------------------------------------
__global__ __launch_bounds__(256) void cast_f32_bf16(
        const float* __restrict__ in, unsigned short* __restrict__ out, int n8) {
    int i = blockIdx.x * 256 + threadIdx.x;
    if (i >= n8) return;
    const float4* p = (const float4*)in + 2 * (size_t)i;
    float4 a = p[0], b = p[1];
    us8 o;
    o[0] = f2bf(a.x); o[1] = f2bf(a.y); o[2] = f2bf(a.z); o[3] = f2bf(a.w);
    o[4] = f2bf(b.x); o[5] = f2bf(b.y); o[6] = f2bf(b.z); o[7] = f2bf(b.w);
    *(us8*)(out + (size_t)i * 8) = o;
}

// ---------------------------------------------------------------------------
// bf16 MFMA GEMM (m97 structure): C[m,n] = sum_k A[m,k]*W[n,k] + bias[n]
//                                            (+ resid[m,n] if resid != null)
// A: M x K bf16 row-major.  W: N x K bf16 row-major (torch Linear weight).
// 128x128 tile, BK=32, 256 threads = 4 waves in 2x2, 4x4 16x16 frags/wave.
// Staging via global_load_lds width=16 (LDS layout = row-major, unpadded,
// exactly the lane order the hardware writes: base + lane*16B).
// ---------------------------------------------------------------------------
#define GBM 128
#define GBN 128
#define GBK 32
__global__ __launch_bounds__(256) void gemm_mfma(
        const unsigned short* __restrict__ A, const unsigned short* __restrict__ W,
        const float* __restrict__ bias, const float* __restrict__ resid,
        float* __restrict__ C, int M, int N, int K) {
    __shared__ unsigned short As[GBM * GBK];   // 8192 B
    __shared__ unsigned short Ws[GBN * GBK];   // 8192 B
    const int tid  = threadIdx.x;
    const int lane = tid & 63;
    const int wave = tid >> 6;                 // 0..3
    const int wm   = wave & 1;                 // wave row (2x2 wave grid)
    const int wn   = wave >> 1;                // wave col
    const int bm   = blockIdx.y * GBM;
    const int bn   = blockIdx.x * GBN;

    f32x4 acc[4][4] = {};

    const int ldr = lane >> 2;        // 0..15: row within a 16-row group
    const int ldc = (lane & 3) * 8;   // bf16 k-offset for the 16B load

    for (int k0 = 0; k0 < K; k0 += GBK) {
        #pragma unroll
        for (int p = 0; p < 2; p++) {
            const int row = p * 64 + wave * 16 + ldr;
            const unsigned short* gsA = A + (size_t)(bm + row) * K + k0 + ldc;
            const unsigned short* gsW = W + (size_t)(bn + row) * K + k0 + ldc;
            __builtin_amdgcn_global_load_lds(
                (const __attribute__((address_space(1))) unsigned int*)gsA,
                (__attribute__((address_space(3))) unsigned int*)(As + (size_t)(p * 64 + wave * 16) * GBK),
                16, 0, 0);
            __builtin_amdgcn_global_load_lds(
                (const __attribute__((address_space(1))) unsigned int*)gsW,
                (__attribute__((address_space(3))) unsigned int*)(Ws + (size_t)(p * 64 + wave * 16) * GBK),
                16, 0, 0);
        }
        __syncthreads();

        const int fr = lane & 15;          // frag row (m or n within 16)
        const int fk = (lane >> 4) * 8;    // frag k-offset
        bf16x8 af[4], bfr[4];
        #pragma unroll
        for (int t = 0; t < 4; t++) {
            af[t]  = *(const bf16x8*)&As[(wm * 64 + t * 16 + fr) * GBK + fk];
            bfr[t] = *(const bf16x8*)&Ws[(wn * 64 + t * 16 + fr) * GBK + fk];
        }
        #pragma unroll
        for (int i = 0; i < 4; i++)
            #pragma unroll
            for (int j = 0; j < 4; j++)
                acc[i][j] = __builtin_amdgcn_mfma_f32_16x16x32_bf16(
                                af[i], bfr[j], acc[i][j], 0, 0, 0);
        __syncthreads();
    }

    // epilogue: C/D layout col=lane&15, row=(lane>>4)*4+reg
    const int col0 = lane & 15;
    const int quad = lane >> 4;
    #pragma unroll
    for (int j = 0; j < 4; j++) {
        const int n = bn + wn * 64 + j * 16 + col0;
        const float bv = bias[n];
        #pragma unroll
        for (int i = 0; i < 4; i++) {
            #pragma unroll
            for (int r = 0; r < 4; r++) {
                const int m = bm + wm * 64 + i * 16 + quad * 4 + r;
                float v = acc[i][j][r] + bv;
                size_t off = (size_t)m * N + n;
                if (resid) v += resid[off];
                C[off] = v;
            }
        }
    }
}

// ---------------------------------------------------------------------------
// Twiddle tables, per-stage-concatenated so butterfly reads are consecutive
// in pos (conflict-free / broadcast). Entry p: stage s = log2-floor(p+1),
// pos = p+1 - 2^s, value exp(-i*pi*pos/2^s). 1023 entries.
// ---------------------------------------------------------------------------
__device__ inline void build_twiddles(float* twr, float* twi, int tid) {
    for (int p = tid; p < 1023; p += 256) {
        int s = 31 - __clz(p + 1);
        int half = 1 << s;
        int pos = p + 1 - half;
        float ang = -3.14159265358979323846f * (float)pos / (float)half;
        float sn, cs;
        __sincosf(ang, &sn, &cs);
        twr[p] = cs; twi[p] = sn;
    }
}

// In-LDS 1024-point complex FFT, 256 threads, table-driven.
// tsign = +1 forward, -1 inverse (inverse does NOT scale by 1/N).
__device__ inline void fft1024_t(float* re, float* im,
                                 const float* twr, const float* twi,
                                 int tid, float tsign) {
    for (int i = tid; i < 1024; i += 256) {
        int r = __brev(i) >> 22;
        if (i < r) {
            float tr = re[i]; re[i] = re[r]; re[r] = tr;
            float ti = im[i]; im[i] = im[r]; im[r] = ti;
        }
    }
    __syncthreads();
    for (int s = 0; s < 10; s++) {
        const int half = 1 << s;
        const int toff = half - 1;
        #pragma unroll
        for (int jj = 0; jj < 2; jj++) {
            int j = tid + jj * 256;          // j in [0, 512)
            int pos = j & (half - 1);
            int i1 = ((j >> s) << (s + 1)) + pos;
            int i2 = i1 + half;
            float cs = twr[toff + pos];
            float sn = twi[toff + pos] * tsign;
            float xr = re[i2], xi = im[i2];
            float tr = xr * cs - xi * sn;
            float ti = xr * sn + xi * cs;
            float ur = re[i1], ui = im[i1];
            re[i1] = ur + tr; im[i1] = ui + ti;
            re[i2] = ur - tr; im[i2] = ui - ti;
        }
        __syncthreads();
    }
}

// ---------------------------------------------------------------------------
// Bind: normalize keys, pack z = k_hat + i*v, ONE 1024-pt FFT, unpack the two
// real-signal spectra (Kf = even part, Vf = odd part), write P = Kf*Vf.
// ---------------------------------------------------------------------------
__global__ __launch_bounds__(256) void bind_fft_kernel(
        const float* __restrict__ Kraw, const float* __restrict__ V,
        float* __restrict__ P) {
    __shared__ float zre[1024], zim[1024];
    __shared__ float twr[1023], twi[1023];
    __shared__ float red[256];
    const int token = blockIdx.x;
    const int tid = threadIdx.x;

    build_twiddles(twr, twi, tid);

    const float* krow = Kraw + (size_t)token * D_SZ;
    const float* vrow = V    + (size_t)token * D_SZ;
    float ss = 0.0f;
    for (int i = tid; i < 1024; i += 256) {
        float kv = krow[i];
        zre[i] = kv;
        zim[i] = vrow[i];
        ss += kv * kv;
    }
    red[tid] = ss;
    __syncthreads();
    for (int s = 128; s > 0; s >>= 1) {
        if (tid < s) red[tid] += red[tid + s];
        __syncthreads();
    }
    const float scale = 1.0f / fmaxf(sqrtf(red[0]), 1e-12f);
    __syncthreads();
    for (int i = tid; i < 1024; i += 256) zre[i] *= scale;
    __syncthreads();

    fft1024_t(zre, zim, twr, twi, tid, +1.0f);

    // unpack: K spectrum A[n]=(Z[n]+conj(Z[N-n]))/2, V spectrum
    // B[n]=(Z[n]-conj(Z[N-n]))/(2i); then P = A*B.
    float2* Po = (float2*)(P + (size_t)token * CCH);
    for (int bin = tid; bin < NBINS; bin += 256) {
        int m = (1024 - bin) & 1023;
        float zr = zre[bin], zi = zim[bin];
        float yr = zre[m],  yi = zim[m];
        float ar = 0.5f * (zr + yr);
        float ai = 0.5f * (zi - yi);
        float br = 0.5f * (zi + yi);
        float bi = 0.5f * (yr - zr);
        Po[bin] = make_float2(ar * br - ai * bi, ar * bi + ai * br);
    }
}

// ---------------------------------------------------------------------------
// Cumsum over t (chunked two-pass).
// ---------------------------------------------------------------------------
__global__ __launch_bounds__(256) void cumsum_local(
        float* __restrict__ S, float* __restrict__ totals) {
    const int c = blockIdx.x * 256 + threadIdx.x;
    if (c >= CCH) return;
    const int chunk = blockIdx.y;
    const int b = blockIdx.z;
    size_t p = ((size_t)b * L_SZ + (size_t)chunk * TLEN) * CCH + c;
    float acc = 0.0f;
    #pragma unroll 4
    for (int t = 0; t < TLEN; t++) {
        acc += S[p];
        S[p] = acc;
        p += CCH;
    }
    totals[((size_t)b * TCH + chunk) * CCH + c] = acc;
}

__global__ __launch_bounds__(256) void cumsum_add(
        float* __restrict__ S, const float* __restrict__ totals) {
    const int c = blockIdx.x * 256 + threadIdx.x;
    if (c >= CCH) return;
    const int chunk = blockIdx.y;
    if (chunk == 0) return;
    const int b = blockIdx.z;
    float off = 0.0f;
    for (int j = 0; j < chunk; j++)
        off += totals[((size_t)b * TCH + j) * CCH + c];
    size_t p = ((size_t)b * L_SZ + (size_t)chunk * TLEN) * CCH + c;
    #pragma unroll 4
    for (int t = 0; t < TLEN; t++) {
        S[p] += off;
        p += CCH;
    }
}

// ---------------------------------------------------------------------------
// Unbind: recompute normalized-key FFT, Rf = S*conj(Kf), Hermitian extend,
// inverse FFT, /sqrt(t+1), LayerNorm -> bf16 RLN (feeds final MFMA GEMM).
// ---------------------------------------------------------------------------
__global__ __launch_bounds__(256) void unbind_ln_kernel(
        const float* __restrict__ S, const float* __restrict__ Kraw,
        const float* __restrict__ ln_g, const float* __restrict__ ln_b,
        unsigned short* __restrict__ RLNb) {
    __shared__ float kre[1024], kim[1024];
    __shared__ float re[1024], im[1024];
    __shared__ float twr[1023], twi[1023];
    __shared__ float red1[256], red2[256];
    const int token = blockIdx.x;
    const int tid = threadIdx.x;
    const int t = token & (L_SZ - 1);

    build_twiddles(twr, twi, tid);

    const float* krow = Kraw + (size_t)token * D_SZ;
    float ss = 0.0f;
    for (int i = tid; i < 1024; i += 256) {
        float v = krow[i];
        kre[i] = v; kim[i] = 0.0f;
        ss += v * v;
    }
    red1[tid] = ss;
    __syncthreads();
    for (int s = 128; s > 0; s >>= 1) {
        if (tid < s) red1[tid] += red1[tid + s];
        __syncthreads();
    }
    const float scale = 1.0f / fmaxf(sqrtf(red1[0]), 1e-12f);
    __syncthreads();
    for (int i = tid; i < 1024; i += 256) kre[i] *= scale;
    __syncthreads();
    fft1024_t(kre, kim, twr, twi, tid, +1.0f);

    // Rf = S * conj(Kf) on bins 0..512
    const float2* Srow = (const float2*)(S + (size_t)token * CCH);
    for (int bin = tid; bin < NBINS; bin += 256) {
        float2 s2 = Srow[bin];
        float kr = kre[bin], ki = kim[bin];
        re[bin] = s2.x * kr + s2.y * ki;
        im[bin] = s2.y * kr - s2.x * ki;
    }
    __syncthreads();
    for (int n = 513 + tid; n < 1024; n += 256) {
        re[n] = re[1024 - n];
        im[n] = -im[1024 - n];
    }
    __syncthreads();

    fft1024_t(re, im, twr, twi, tid, -1.0f);   // inverse (unscaled)

    const float posscale = (1.0f / 1024.0f) * rsqrtf((float)(t + 1));
    float rv[4];
    float sum = 0.0f, sumsq = 0.0f;
    #pragma unroll
    for (int i = 0; i < 4; i++) {
        int d = tid + i * 256;
        float v = re[d] * posscale;
        rv[i] = v;
        sum += v;
        sumsq += v * v;
    }
    red1[tid] = sum; red2[tid] = sumsq;
    __syncthreads();
    for (int s = 128; s > 0; s >>= 1) {
        if (tid < s) { red1[tid] += red1[tid + s]; red2[tid] += red2[tid + s]; }
        __syncthreads();
    }
    const float mu = red1[0] * (1.0f / 1024.0f);
    const float var = red2[0] * (1.0f / 1024.0f) - mu * mu;
    const float rstd = rsqrtf(var + 1e-5f);

    unsigned short* outp = RLNb + (size_t)token * D_SZ;
    #pragma unroll
    for (int i = 0; i < 4; i++) {
        int d = tid + i * 256;
        outp[d] = f2bf((rv[i] - mu) * rstd * ln_g[d] + ln_b[d]);
    }
}

// ---------------------------------------------------------------------------
// Workspace (bytes):
//   Kraw   fp32 M*D    = 64.0 MB
//   V      fp32 M*D    = 64.0 MB  (dead after bind; first 32 MB reused as RLNb)
//   P      fp32 M*CCH  = 67.2 MB  (cumsum in place)
//   totals fp32        =  0.5 MB
//   xb     bf16 M*D    = 32.0 MB
//   Wkb/Wvb/Wob bf16   =  6.0 MB
//   total ~= 234 MB
// ---------------------------------------------------------------------------
extern "C" void kernel_launch(void* const* d_in, const int* in_sizes, int n_in,
                              void* d_out, int out_size, void* d_ws, size_t ws_size,
                              hipStream_t stream) {
    (void)in_sizes; (void)n_in; (void)out_size; (void)ws_size;
    const float* x    = (const float*)d_in[0];
    const float* Wk   = (const float*)d_in[1];
    const float* bk   = (const float*)d_in[2];
    const float* Wv   = (const float*)d_in[3];
    const float* bv   = (const float*)d_in[4];
    const float* ln_g = (const float*)d_in[5];
    const float* ln_b = (const float*)d_in[6];
    const float* Wo   = (const float*)d_in[7];
    const float* bo   = (const float*)d_in[8];
    float* out = (float*)d_out;

    char* w = (char*)d_ws;
    float* Kraw   = (float*)w;  w += (size_t)M_SZ * D_SZ * 4;
    float* V      = (float*)w;  w += (size_t)M_SZ * D_SZ * 4;
    float* P      = (float*)w;  w += (size_t)M_SZ * CCH * 4;
    float* totals = (float*)w;  w += (size_t)B_SZ * TCH * CCH * 4;
    unsigned short* xb  = (unsigned short*)w;  w += (size_t)M_SZ * D_SZ * 2;
    unsigned short* Wkb = (unsigned short*)w;  w += (size_t)D_SZ * D_SZ * 2;
    unsigned short* Wvb = (unsigned short*)w;  w += (size_t)D_SZ * D_SZ * 2;
    unsigned short* Wob = (unsigned short*)w;  w += (size_t)D_SZ * D_SZ * 2;
    unsigned short* RLNb = (unsigned short*)V;  // overlays dead V

    const int n8x = M_SZ * D_SZ / 8;   // 2,097,152
    const int n8w = D_SZ * D_SZ / 8;   // 131,072
    cast_f32_bf16<<<n8x / 256, 256, 0, stream>>>(x,  xb,  n8x);
    cast_f32_bf16<<<n8w / 256, 256, 0, stream>>>(Wk, Wkb, n8w);
    cast_f32_bf16<<<n8w / 256, 256, 0, stream>>>(Wv, Wvb, n8w);
    cast_f32_bf16<<<n8w / 256, 256, 0, stream>>>(Wo, Wob, n8w);

    dim3 ggrid(D_SZ / GBN, M_SZ / GBM);   // (8, 128)
    gemm_mfma<<<ggrid, 256, 0, stream>>>(xb, Wkb, bk, nullptr, Kraw, M_SZ, D_SZ, D_SZ);
    gemm_mfma<<<ggrid, 256, 0, stream>>>(xb, Wvb, bv, nullptr, V,    M_SZ, D_SZ, D_SZ);

    bind_fft_kernel<<<M_SZ, 256, 0, stream>>>(Kraw, V, P);

    dim3 cgrid((CCH + 255) / 256, TCH, B_SZ);
    cumsum_local<<<cgrid, 256, 0, stream>>>(P, totals);
    cumsum_add<<<cgrid, 256, 0, stream>>>(P, totals);

    unbind_ln_kernel<<<M_SZ, 256, 0, stream>>>(P, Kraw, ln_g, ln_b, RLNb);

    gemm_mfma<<<ggrid, 256, 0, stream>>>(RLNb, Wob, bo, x, out, M_SZ, D_SZ, D_SZ);
}

// Round 4
// 532.246 us; speedup vs baseline: 3.7844x; 1.5776x over previous
//
#include <hip/hip_runtime.h>
#include <math.h>

// Problem constants (from reference): B=4, L=4096, D=1024
#define B_SZ 4
#define L_SZ 4096
#define D_SZ 1024
#define M_SZ (B_SZ * L_SZ)      // 16384 tokens
#define NBINS 513               // rfft bins for D=1024
#define CCH   (2 * NBINS)       // 1026 float channels per token (interleaved re,im)
#define TCH 32                  // cumsum chunks over L
#define TLEN (L_SZ / TCH)       // 128 timesteps per chunk

typedef short bf16x8 __attribute__((ext_vector_type(8)));
typedef float f32x4  __attribute__((ext_vector_type(4)));
typedef unsigned short us8 __attribute__((ext_vector_type(8)));

// round-to-nearest-even f32 -> bf16
__device__ inline unsigned short f2bf(float f) {
    unsigned int u = __float_as_uint(f);
    u += 0x7fffu + ((u >> 16) & 1u);
    return (unsigned short)(u >> 16);
}

// ---------------------------------------------------------------------------
// f32 -> bf16 cast, 8 elements/thread
// ---------------------------------------------------------------------------
__global__ __launch_bounds__(256) void cast_f32_bf16(
        const float* __restrict__ in, unsigned short* __restrict__ out, int n8) {
    int i = blockIdx.x * 256 + threadIdx.x;
    if (i >= n8) return;
    const float4* p = (const float4*)in + 2 * (size_t)i;
    float4 a = p[0], b = p[1];
    us8 o;
    o[0] = f2bf(a.x); o[1] = f2bf(a.y); o[2] = f2bf(a.z); o[3] = f2bf(a.w);
    o[4] = f2bf(b.x); o[5] = f2bf(b.y); o[6] = f2bf(b.z); o[7] = f2bf(b.w);
    *(us8*)(out + (size_t)i * 8) = o;
}

// ---------------------------------------------------------------------------
// bf16 MFMA GEMM (m97 structure): unchanged from round 3.
// ---------------------------------------------------------------------------
#define GBM 128
#define GBN 128
#define GBK 32
__global__ __launch_bounds__(256) void gemm_mfma(
        const unsigned short* __restrict__ A, const unsigned short* __restrict__ W,
        const float* __restrict__ bias, const float* __restrict__ resid,
        float* __restrict__ C, int M, int N, int K) {
    __shared__ unsigned short As[GBM * GBK];   // 8192 B
    __shared__ unsigned short Ws[GBN * GBK];   // 8192 B
    const int tid  = threadIdx.x;
    const int lane = tid & 63;
    const int wave = tid >> 6;                 // 0..3
    const int wm   = wave & 1;
    const int wn   = wave >> 1;
    const int bm   = blockIdx.y * GBM;
    const int bn   = blockIdx.x * GBN;

    f32x4 acc[4][4] = {};

    const int ldr = lane >> 2;
    const int ldc = (lane & 3) * 8;

    for (int k0 = 0; k0 < K; k0 += GBK) {
        #pragma unroll
        for (int p = 0; p < 2; p++) {
            const int row = p * 64 + wave * 16 + ldr;
            const unsigned short* gsA = A + (size_t)(bm + row) * K + k0 + ldc;
            const unsigned short* gsW = W + (size_t)(bn + row) * K + k0 + ldc;
            __builtin_amdgcn_global_load_lds(
                (const __attribute__((address_space(1))) unsigned int*)gsA,
                (__attribute__((address_space(3))) unsigned int*)(As + (size_t)(p * 64 + wave * 16) * GBK),
                16, 0, 0);
            __builtin_amdgcn_global_load_lds(
                (const __attribute__((address_space(1))) unsigned int*)gsW,
                (__attribute__((address_space(3))) unsigned int*)(Ws + (size_t)(p * 64 + wave * 16) * GBK),
                16, 0, 0);
        }
        __syncthreads();

        const int fr = lane & 15;
        const int fk = (lane >> 4) * 8;
        bf16x8 af[4], bfr[4];
        #pragma unroll
        for (int t = 0; t < 4; t++) {
            af[t]  = *(const bf16x8*)&As[(wm * 64 + t * 16 + fr) * GBK + fk];
            bfr[t] = *(const bf16x8*)&Ws[(wn * 64 + t * 16 + fr) * GBK + fk];
        }
        #pragma unroll
        for (int i = 0; i < 4; i++)
            #pragma unroll
            for (int j = 0; j < 4; j++)
                acc[i][j] = __builtin_amdgcn_mfma_f32_16x16x32_bf16(
                                af[i], bfr[j], acc[i][j], 0, 0, 0);
        __syncthreads();
    }

    const int col0 = lane & 15;
    const int quad = lane >> 4;
    #pragma unroll
    for (int j = 0; j < 4; j++) {
        const int n = bn + wn * 64 + j * 16 + col0;
        const float bv = bias[n];
        #pragma unroll
        for (int i = 0; i < 4; i++) {
            #pragma unroll
            for (int r = 0; r < 4; r++) {
                const int m = bm + wm * 64 + i * 16 + quad * 4 + r;
                float v = acc[i][j][r] + bv;
                size_t off = (size_t)m * N + n;
                if (resid) v += resid[off];
                C[off] = v;
            }
        }
    }
}

// ---------------------------------------------------------------------------
// Stockham radix-4 1024-pt FFT. 256 threads, 4 complex/thread in registers,
// 5 stages, exchanges via two swizzled float2 LDS buffers (conflict-free:
// phi(a) = a ^ ((a>>4)&15) makes every stage's access uniform over banks).
// Input:  v[k] = x[tid + 256k] (natural time order, registers)
// Output: v[e] = X[tid + 256e] (natural freq order, registers)
// SIGN = -1 forward (numpy fft), +1 inverse (unscaled).
// Caller must __syncthreads() before calling if bA was just written/read.
// ---------------------------------------------------------------------------
#define SWZ(a) ((a) ^ (((a) >> 4) & 15))

struct cplx { float r, i; };
__device__ inline cplx cmul(cplx a, cplx b) {
    return {a.r * b.r - a.i * b.i, a.r * b.i + a.i * b.r};
}

__device__ inline void r4bfly(cplx v[4], float s) {
    cplx t0 {v[0].r + v[2].r, v[0].i + v[2].i};
    cplx t1 {v[0].r - v[2].r, v[0].i - v[2].i};
    cplx t2 {v[1].r + v[3].r, v[1].i + v[3].i};
    cplx t3 {v[1].r - v[3].r, v[1].i - v[3].i};
    cplx j3 {-s * t3.i, s * t3.r};     // s*i * t3
    v[0] = {t0.r + t2.r, t0.i + t2.i};
    v[2] = {t0.r - t2.r, t0.i - t2.i};
    v[1] = {t1.r + j3.r, t1.i + j3.i};
    v[3] = {t1.r - j3.r, t1.i - j3.i};
}

template<int SIGN>
__device__ inline void fft1024_r(float2* bA, float2* bB, cplx v[4], int tid) {
    const float s = (float)SIGN;
    // stage 0 (Ls=1, d=0, no twiddle)
    r4bfly(v, s);
    {
        const int base = tid << 2;
        #pragma unroll
        for (int e = 0; e < 4; e++)
            bA[SWZ(base + e)] = make_float2(v[e].r, v[e].i);
    }
    __syncthreads();
    float2* cur = bA;
    float2* nxt = bB;
    // stages 1..3
    #pragma unroll
    for (int q = 1; q <= 3; q++) {
        const int Ls = 1 << (2 * q);
        #pragma unroll
        for (int k = 0; k < 4; k++) {
            float2 t = cur[SWZ(tid + (k << 8))];
            v[k] = {t.x, t.y};
        }
        const int d = tid & (Ls - 1);
        const float ang = s * 1.57079632679489662f * (float)d / (float)Ls;
        float sn, cs; __sincosf(ang, &sn, &cs);
        cplx w1 {cs, sn};
        cplx w2 = cmul(w1, w1);
        cplx w3 = cmul(w2, w1);
        v[1] = cmul(v[1], w1);
        v[2] = cmul(v[2], w2);
        v[3] = cmul(v[3], w3);
        r4bfly(v, s);
        const int base = ((tid >> (2 * q)) << (2 * q + 2)) + d;
        #pragma unroll
        for (int e = 0; e < 4; e++)
            nxt[SWZ(base + (e << (2 * q)))] = make_float2(v[e].r, v[e].i);
        float2* tmp = cur; cur = nxt; nxt = tmp;
        __syncthreads();
    }
    // stage 4 (Ls=256): read, butterfly, leave in registers
    #pragma unroll
    for (int k = 0; k < 4; k++) {
        float2 t = cur[SWZ(tid + (k << 8))];
        v[k] = {t.x, t.y};
    }
    {
        const float ang = s * 1.57079632679489662f * (float)tid / 256.0f;
        float sn, cs; __sincosf(ang, &sn, &cs);
        cplx w1 {cs, sn};
        cplx w2 = cmul(w1, w1);
        cplx w3 = cmul(w2, w1);
        v[1] = cmul(v[1], w1);
        v[2] = cmul(v[2], w2);
        v[3] = cmul(v[3], w3);
        r4bfly(v, s);
    }
    // v[e] = X[tid + 256e]
}

// ---------------------------------------------------------------------------
// Bind: normalize keys, pack z = k_hat + i*v, one forward FFT, unpack the two
// real-signal spectra (Kf even part, Vf odd part), write P = Kf*Vf.
// ---------------------------------------------------------------------------
__global__ __launch_bounds__(256) void bind_fft_kernel(
        const float* __restrict__ Kraw, const float* __restrict__ V,
        float* __restrict__ P) {
    __shared__ float2 bA[1024], bB[1024];
    __shared__ float red[256];
    const int token = blockIdx.x;
    const int tid = threadIdx.x;

    const float* krow = Kraw + (size_t)token * D_SZ;
    const float* vrow = V    + (size_t)token * D_SZ;
    float kv[4], vv[4];
    float ss = 0.0f;
    #pragma unroll
    for (int k = 0; k < 4; k++) {
        kv[k] = krow[tid + (k << 8)];
        vv[k] = vrow[tid + (k << 8)];
        ss += kv[k] * kv[k];
    }
    red[tid] = ss;
    __syncthreads();
    for (int sft = 128; sft > 0; sft >>= 1) {
        if (tid < sft) red[tid] += red[tid + sft];
        __syncthreads();
    }
    const float scale = 1.0f / fmaxf(sqrtf(red[0]), 1e-12f);

    cplx z[4];
    #pragma unroll
    for (int k = 0; k < 4; k++) z[k] = {kv[k] * scale, vv[k]};

    __syncthreads();
    fft1024_r<-1>(bA, bB, z, tid);

    // store Z into bA (free: stage-4 only read bB), then unpack pairs
    #pragma unroll
    for (int e = 0; e < 4; e++)
        bA[SWZ(tid + (e << 8))] = make_float2(z[e].r, z[e].i);
    __syncthreads();

    float2* Po = (float2*)(P + (size_t)token * CCH);
    for (int bin = tid; bin < NBINS; bin += 256) {
        float2 Zb = bA[SWZ(bin)];
        float2 Zm = bA[SWZ((1024 - bin) & 1023)];
        float ar = 0.5f * (Zb.x + Zm.x);
        float ai = 0.5f * (Zb.y - Zm.y);
        float br = 0.5f * (Zb.y + Zm.y);
        float bi = 0.5f * (Zm.x - Zb.x);
        Po[bin] = make_float2(ar * br - ai * bi, ar * bi + ai * br);
    }
}

// ---------------------------------------------------------------------------
// Cumsum pass 1: in-place local cumsum within each t-chunk + chunk totals.
// ---------------------------------------------------------------------------
__global__ __launch_bounds__(256) void cumsum_local(
        float* __restrict__ S, float* __restrict__ totals) {
    const int c = blockIdx.x * 256 + threadIdx.x;
    if (c >= CCH) return;
    const int chunk = blockIdx.y;
    const int b = blockIdx.z;
    size_t p = ((size_t)b * L_SZ + (size_t)chunk * TLEN) * CCH + c;
    float acc = 0.0f;
    #pragma unroll 4
    for (int t = 0; t < TLEN; t++) {
        acc += S[p];
        S[p] = acc;
        p += CCH;
    }
    totals[((size_t)b * TCH + chunk) * CCH + c] = acc;
}

// Pass 2: turn chunk totals into EXCLUSIVE prefix offsets (in place).
// Grid: ((CCH+255)/256, B). unbind adds these during its S read, so the
// old full-array cumsum_add pass (134 MB of traffic) is eliminated.
__global__ __launch_bounds__(256) void scan_totals(float* __restrict__ totals) {
    const int c = blockIdx.x * 256 + threadIdx.x;
    if (c >= CCH) return;
    const int b = blockIdx.y;
    float acc = 0.0f;
    for (int ch = 0; ch < TCH; ch++) {
        size_t idx = ((size_t)b * TCH + ch) * CCH + c;
        float v = totals[idx];
        totals[idx] = acc;
        acc += v;
    }
}

// ---------------------------------------------------------------------------
// Unbind: recompute normalized-key FFT, Rf = (S_local+off)*conj(Kf),
// Hermitian extend, inverse FFT, /sqrt(t+1), LayerNorm -> bf16 RLN.
// ---------------------------------------------------------------------------
__global__ __launch_bounds__(256) void unbind_ln_kernel(
        const float* __restrict__ P, const float* __restrict__ totals,
        const float* __restrict__ Kraw,
        const float* __restrict__ ln_g, const float* __restrict__ ln_b,
        unsigned short* __restrict__ RLNb) {
    __shared__ float2 bA[1024], bB[1024];
    __shared__ float red1[256], red2[256];
    const int token = blockIdx.x;
    const int tid = threadIdx.x;
    const int b = token >> 12;          // token / L_SZ
    const int t = token & (L_SZ - 1);
    const int chunk = t >> 7;           // t / TLEN

    // ---- key FFT from registers ----
    const float* krow = Kraw + (size_t)token * D_SZ;
    float kv[4];
    float ss = 0.0f;
    #pragma unroll
    for (int k = 0; k < 4; k++) {
        kv[k] = krow[tid + (k << 8)];
        ss += kv[k] * kv[k];
    }
    red1[tid] = ss;
    __syncthreads();
    for (int sft = 128; sft > 0; sft >>= 1) {
        if (tid < sft) red1[tid] += red1[tid + sft];
        __syncthreads();
    }
    const float scale = 1.0f / fmaxf(sqrtf(red1[0]), 1e-12f);

    cplx kz[4];
    #pragma unroll
    for (int k = 0; k < 4; k++) kz[k] = {kv[k] * scale, 0.0f};

    __syncthreads();
    fft1024_r<-1>(bA, bB, kz, tid);     // kz[e] = Kf[tid + 256e]

    // ---- Rf = (S_local + off) * conj(Kf), bins 0..512, into bA ----
    const float2* Srow   = (const float2*)(P + (size_t)token * CCH);
    const float2* offrow = (const float2*)(totals + ((size_t)b * TCH + chunk) * CCH);
    #pragma unroll
    for (int e = 0; e < 3; e++) {
        const int bin = tid + (e << 8);
        if (bin < NBINS) {
            float2 s2 = Srow[bin];
            float2 o2 = offrow[bin];
            float sr = s2.x + o2.x, si = s2.y + o2.y;
            float kr = kz[e].r, ki = kz[e].i;
            bA[SWZ(bin)] = make_float2(sr * kr + si * ki, si * kr - sr * ki);
        }
    }
    __syncthreads();
    // Hermitian extension 513..1023
    for (int n = 513 + tid; n < 1024; n += 256) {
        float2 c = bA[SWZ(1024 - n)];
        bA[SWZ(n)] = make_float2(c.x, -c.y);
    }
    __syncthreads();

    // ---- inverse FFT ----
    cplx rz[4];
    #pragma unroll
    for (int k = 0; k < 4; k++) {
        float2 c = bA[SWZ(tid + (k << 8))];
        rz[k] = {c.x, c.y};
    }
    __syncthreads();                    // all reads of bA done before fft rewrites it
    fft1024_r<1>(bA, bB, rz, tid);      // rz[e].r = r[tid + 256e] * 1024

    // ---- /sqrt(t+1), LayerNorm, bf16 store ----
    const float posscale = (1.0f / 1024.0f) * rsqrtf((float)(t + 1));
    float rv[4];
    float sum = 0.0f, sumsq = 0.0f;
    #pragma unroll
    for (int e = 0; e < 4; e++) {
        float v = rz[e].r * posscale;
        rv[e] = v;
        sum += v;
        sumsq += v * v;
    }
    red1[tid] = sum; red2[tid] = sumsq;
    __syncthreads();
    for (int sft = 128; sft > 0; sft >>= 1) {
        if (tid < sft) { red1[tid] += red1[tid + sft]; red2[tid] += red2[tid + sft]; }
        __syncthreads();
    }
    const float mu = red1[0] * (1.0f / 1024.0f);
    const float var = red2[0] * (1.0f / 1024.0f) - mu * mu;
    const float rstd = rsqrtf(var + 1e-5f);

    unsigned short* outp = RLNb + (size_t)token * D_SZ;
    #pragma unroll
    for (int e = 0; e < 4; e++) {
        const int d = tid + (e << 8);
        outp[d] = f2bf((rv[e] - mu) * rstd * ln_g[d] + ln_b[d]);
    }
}

// ---------------------------------------------------------------------------
// Workspace (bytes):
//   Kraw   fp32 M*D    = 64.0 MB
//   V      fp32 M*D    = 64.0 MB  (dead after bind; reused as bf16 RLN)
//   P      fp32 M*CCH  = 67.2 MB  (local cumsum in place)
//   totals fp32        =  0.5 MB  (chunk totals -> exclusive offsets)
//   xb     bf16 M*D    = 32.0 MB
//   Wkb/Wvb/Wob bf16   =  6.0 MB
//   total ~= 234 MB
// ---------------------------------------------------------------------------
extern "C" void kernel_launch(void* const* d_in, const int* in_sizes, int n_in,
                              void* d_out, int out_size, void* d_ws, size_t ws_size,
                              hipStream_t stream) {
    (void)in_sizes; (void)n_in; (void)out_size; (void)ws_size;
    const float* x    = (const float*)d_in[0];
    const float* Wk   = (const float*)d_in[1];
    const float* bk   = (const float*)d_in[2];
    const float* Wv   = (const float*)d_in[3];
    const float* bv   = (const float*)d_in[4];
    const float* ln_g = (const float*)d_in[5];
    const float* ln_b = (const float*)d_in[6];
    const float* Wo   = (const float*)d_in[7];
    const float* bo   = (const float*)d_in[8];
    float* out = (float*)d_out;

    char* w = (char*)d_ws;
    float* Kraw   = (float*)w;  w += (size_t)M_SZ * D_SZ * 4;
    float* V      = (float*)w;  w += (size_t)M_SZ * D_SZ * 4;
    float* P      = (float*)w;  w += (size_t)M_SZ * CCH * 4;
    float* totals = (float*)w;  w += (size_t)B_SZ * TCH * CCH * 4;
    unsigned short* xb  = (unsigned short*)w;  w += (size_t)M_SZ * D_SZ * 2;
    unsigned short* Wkb = (unsigned short*)w;  w += (size_t)D_SZ * D_SZ * 2;
    unsigned short* Wvb = (unsigned short*)w;  w += (size_t)D_SZ * D_SZ * 2;
    unsigned short* Wob = (unsigned short*)w;  w += (size_t)D_SZ * D_SZ * 2;
    unsigned short* RLNb = (unsigned short*)V;  // overlays dead V

    const int n8x = M_SZ * D_SZ / 8;
    const int n8w = D_SZ * D_SZ / 8;
    cast_f32_bf16<<<n8x / 256, 256, 0, stream>>>(x,  xb,  n8x);
    cast_f32_bf16<<<n8w / 256, 256, 0, stream>>>(Wk, Wkb, n8w);
    cast_f32_bf16<<<n8w / 256, 256, 0, stream>>>(Wv, Wvb, n8w);
    cast_f32_bf16<<<n8w / 256, 256, 0, stream>>>(Wo, Wob, n8w);

    dim3 ggrid(D_SZ / GBN, M_SZ / GBM);   // (8, 128)
    gemm_mfma<<<ggrid, 256, 0, stream>>>(xb, Wkb, bk, nullptr, Kraw, M_SZ, D_SZ, D_SZ);
    gemm_mfma<<<ggrid, 256, 0, stream>>>(xb, Wvb, bv, nullptr, V,    M_SZ, D_SZ, D_SZ);

    bind_fft_kernel<<<M_SZ, 256, 0, stream>>>(Kraw, V, P);

    dim3 cgrid((CCH + 255) / 256, TCH, B_SZ);
    cumsum_local<<<cgrid, 256, 0, stream>>>(P, totals);
    dim3 sgrid((CCH + 255) / 256, B_SZ);
    scan_totals<<<sgrid, 256, 0, stream>>>(totals);

    unbind_ln_kernel<<<M_SZ, 256, 0, stream>>>(P, totals, Kraw, ln_g, ln_b, RLNb);

    gemm_mfma<<<ggrid, 256, 0, stream>>>(RLNb, Wob, bo, x, out, M_SZ, D_SZ, D_SZ);
}

// Round 5
// 508.641 us; speedup vs baseline: 3.9600x; 1.0464x over previous
//
#include <hip/hip_runtime.h>
#include <math.h>

// Problem constants (from reference): B=4, L=4096, D=1024
#define B_SZ 4
#define L_SZ 4096
#define D_SZ 1024
#define M_SZ (B_SZ * L_SZ)      // 16384 tokens
#define NBINS 513               // rfft bins for D=1024
#define CCH   (2 * NBINS)       // 1026 float channels per token (interleaved re,im)
#define TCH 32                  // cumsum chunks over L
#define TLEN (L_SZ / TCH)       // 128 timesteps per chunk

typedef short bf16x8 __attribute__((ext_vector_type(8)));
typedef float f32x4  __attribute__((ext_vector_type(4)));
typedef unsigned short us8 __attribute__((ext_vector_type(8)));

// round-to-nearest-even f32 -> bf16
__device__ inline unsigned short f2bf(float f) {
    unsigned int u = __float_as_uint(f);
    u += 0x7fffu + ((u >> 16) & 1u);
    return (unsigned short)(u >> 16);
}

// ---------------------------------------------------------------------------
// f32 -> bf16 cast, 8 elements/thread
// ---------------------------------------------------------------------------
__global__ __launch_bounds__(256) void cast_f32_bf16(
        const float* __restrict__ in, unsigned short* __restrict__ out, int n8) {
    int i = blockIdx.x * 256 + threadIdx.x;
    if (i >= n8) return;
    const float4* p = (const float4*)in + 2 * (size_t)i;
    float4 a = p[0], b = p[1];
    us8 o;
    o[0] = f2bf(a.x); o[1] = f2bf(a.y); o[2] = f2bf(a.z); o[3] = f2bf(a.w);
    o[4] = f2bf(b.x); o[5] = f2bf(b.y); o[6] = f2bf(b.z); o[7] = f2bf(b.w);
    *(us8*)(out + (size_t)i * 8) = o;
}

// ---------------------------------------------------------------------------
// bf16 MFMA GEMM, 128x128 tile, BK=32, XCD-swizzled 1D grid.
// A: M x K bf16.  W: (CN*128) x K bf16 (torch Linear layout).  K = 1024 here.
// The logical N axis is split into halves of 1024: cols [0,1024) -> C0/bias0,
// cols [1024,2048) -> C1/bias1 (for the fused K+V projection). For a plain
// GEMM pass C1=C0, bias1=bias0 (CN=8 never reaches the second half).
// resid (fp32, M x 1024) added when non-null.
//
// Swizzle: id -> bx=(id>>3)%CN, by=(id&7)+8*(id/(8*CN)). All blocks sharing
// an A row-tile have id == r (mod 8) -> same XCD under round-robin dispatch;
// per XCD the A working set is 16 row-tiles = 4 MB = one L2.
// ---------------------------------------------------------------------------
#define GBM 128
#define GBN 128
#define GBK 32
template<int CN>
__global__ __launch_bounds__(256) void gemm_mfma(
        const unsigned short* __restrict__ A, const unsigned short* __restrict__ W,
        const float* __restrict__ bias0, const float* __restrict__ bias1,
        const float* __restrict__ resid,
        float* __restrict__ C0, float* __restrict__ C1, int M, int K) {
    __shared__ unsigned short As[GBM * GBK];   // 8192 B
    __shared__ unsigned short Ws[GBN * GBK];   // 8192 B
    const int id   = blockIdx.x;
    const int bx   = (id >> 3) % CN;
    const int by   = (id & 7) + 8 * (id / (8 * CN));
    const int tid  = threadIdx.x;
    const int lane = tid & 63;
    const int wave = tid >> 6;                 // 0..3
    const int wm   = wave & 1;
    const int wn   = wave >> 1;
    const int bm   = by * GBM;
    const int bn   = bx * GBN;

    f32x4 acc[4][4] = {};

    const int ldr = lane >> 2;
    const int ldc = (lane & 3) * 8;

    for (int k0 = 0; k0 < K; k0 += GBK) {
        #pragma unroll
        for (int p = 0; p < 2; p++) {
            const int row = p * 64 + wave * 16 + ldr;
            const unsigned short* gsA = A + (size_t)(bm + row) * K + k0 + ldc;
            const unsigned short* gsW = W + (size_t)(bn + row) * K + k0 + ldc;
            __builtin_amdgcn_global_load_lds(
                (const __attribute__((address_space(1))) unsigned int*)gsA,
                (__attribute__((address_space(3))) unsigned int*)(As + (size_t)(p * 64 + wave * 16) * GBK),
                16, 0, 0);
            __builtin_amdgcn_global_load_lds(
                (const __attribute__((address_space(1))) unsigned int*)gsW,
                (__attribute__((address_space(3))) unsigned int*)(Ws + (size_t)(p * 64 + wave * 16) * GBK),
                16, 0, 0);
        }
        __syncthreads();

        const int fr = lane & 15;
        const int fk = (lane >> 4) * 8;
        bf16x8 af[4], bfr[4];
        #pragma unroll
        for (int t = 0; t < 4; t++) {
            af[t]  = *(const bf16x8*)&As[(wm * 64 + t * 16 + fr) * GBK + fk];
            bfr[t] = *(const bf16x8*)&Ws[(wn * 64 + t * 16 + fr) * GBK + fk];
        }
        #pragma unroll
        for (int i = 0; i < 4; i++)
            #pragma unroll
            for (int j = 0; j < 4; j++)
                acc[i][j] = __builtin_amdgcn_mfma_f32_16x16x32_bf16(
                                af[i], bfr[j], acc[i][j], 0, 0, 0);
        __syncthreads();
    }

    const int col0 = lane & 15;
    const int quad = lane >> 4;
    #pragma unroll
    for (int j = 0; j < 4; j++) {
        const int ng = bn + wn * 64 + j * 16 + col0;   // global col in [0, CN*128)
        const int half = ng >> 10;                     // 0 or 1 (wave-uniform per j)
        const int n = ng & 1023;
        float* __restrict__ Cp = half ? C1 : C0;
        const float bv = half ? bias1[n] : bias0[n];
        #pragma unroll
        for (int i = 0; i < 4; i++) {
            #pragma unroll
            for (int r = 0; r < 4; r++) {
                const int m = bm + wm * 64 + i * 16 + quad * 4 + r;
                float v = acc[i][j][r] + bv;
                size_t off = (size_t)m * 1024 + n;
                if (resid) v += resid[off];
                Cp[off] = v;
            }
        }
    }
}

// ---------------------------------------------------------------------------
// Stockham radix-4 1024-pt FFT. 256 threads, 4 complex/thread in registers,
// 5 stages, exchanges via two swizzled float2 LDS buffers (conflict-free).
// ---------------------------------------------------------------------------
#define SWZ(a) ((a) ^ (((a) >> 4) & 15))

struct cplx { float r, i; };
__device__ inline cplx cmul(cplx a, cplx b) {
    return {a.r * b.r - a.i * b.i, a.r * b.i + a.i * b.r};
}

__device__ inline void r4bfly(cplx v[4], float s) {
    cplx t0 {v[0].r + v[2].r, v[0].i + v[2].i};
    cplx t1 {v[0].r - v[2].r, v[0].i - v[2].i};
    cplx t2 {v[1].r + v[3].r, v[1].i + v[3].i};
    cplx t3 {v[1].r - v[3].r, v[1].i - v[3].i};
    cplx j3 {-s * t3.i, s * t3.r};     // s*i * t3
    v[0] = {t0.r + t2.r, t0.i + t2.i};
    v[2] = {t0.r - t2.r, t0.i - t2.i};
    v[1] = {t1.r + j3.r, t1.i + j3.i};
    v[3] = {t1.r - j3.r, t1.i - j3.i};
}

template<int SIGN>
__device__ inline void fft1024_r(float2* bA, float2* bB, cplx v[4], int tid) {
    const float s = (float)SIGN;
    r4bfly(v, s);
    {
        const int base = tid << 2;
        #pragma unroll
        for (int e = 0; e < 4; e++)
            bA[SWZ(base + e)] = make_float2(v[e].r, v[e].i);
    }
    __syncthreads();
    float2* cur = bA;
    float2* nxt = bB;
    #pragma unroll
    for (int q = 1; q <= 3; q++) {
        const int Ls = 1 << (2 * q);
        #pragma unroll
        for (int k = 0; k < 4; k++) {
            float2 t = cur[SWZ(tid + (k << 8))];
            v[k] = {t.x, t.y};
        }
        const int d = tid & (Ls - 1);
        const float ang = s * 1.57079632679489662f * (float)d / (float)Ls;
        float sn, cs; __sincosf(ang, &sn, &cs);
        cplx w1 {cs, sn};
        cplx w2 = cmul(w1, w1);
        cplx w3 = cmul(w2, w1);
        v[1] = cmul(v[1], w1);
        v[2] = cmul(v[2], w2);
        v[3] = cmul(v[3], w3);
        r4bfly(v, s);
        const int base = ((tid >> (2 * q)) << (2 * q + 2)) + d;
        #pragma unroll
        for (int e = 0; e < 4; e++)
            nxt[SWZ(base + (e << (2 * q)))] = make_float2(v[e].r, v[e].i);
        float2* tmp = cur; cur = nxt; nxt = tmp;
        __syncthreads();
    }
    #pragma unroll
    for (int k = 0; k < 4; k++) {
        float2 t = cur[SWZ(tid + (k << 8))];
        v[k] = {t.x, t.y};
    }
    {
        const float ang = s * 1.57079632679489662f * (float)tid / 256.0f;
        float sn, cs; __sincosf(ang, &sn, &cs);
        cplx w1 {cs, sn};
        cplx w2 = cmul(w1, w1);
        cplx w3 = cmul(w2, w1);
        v[1] = cmul(v[1], w1);
        v[2] = cmul(v[2], w2);
        v[3] = cmul(v[3], w3);
        r4bfly(v, s);
    }
}

// ---------------------------------------------------------------------------
// Bind: normalize keys, pack z = k_hat + i*v, one forward FFT, unpack the two
// real-signal spectra (Kf even part, Vf odd part), write P = Kf*Vf.
// ---------------------------------------------------------------------------
__global__ __launch_bounds__(256) void bind_fft_kernel(
        const float* __restrict__ Kraw, const float* __restrict__ V,
        float* __restrict__ P) {
    __shared__ float2 bA[1024], bB[1024];
    __shared__ float red[256];
    const int token = blockIdx.x;
    const int tid = threadIdx.x;

    const float* krow = Kraw + (size_t)token * D_SZ;
    const float* vrow = V    + (size_t)token * D_SZ;
    float kv[4], vv[4];
    float ss = 0.0f;
    #pragma unroll
    for (int k = 0; k < 4; k++) {
        kv[k] = krow[tid + (k << 8)];
        vv[k] = vrow[tid + (k << 8)];
        ss += kv[k] * kv[k];
    }
    red[tid] = ss;
    __syncthreads();
    for (int sft = 128; sft > 0; sft >>= 1) {
        if (tid < sft) red[tid] += red[tid + sft];
        __syncthreads();
    }
    const float scale = 1.0f / fmaxf(sqrtf(red[0]), 1e-12f);

    cplx z[4];
    #pragma unroll
    for (int k = 0; k < 4; k++) z[k] = {kv[k] * scale, vv[k]};

    __syncthreads();
    fft1024_r<-1>(bA, bB, z, tid);

    #pragma unroll
    for (int e = 0; e < 4; e++)
        bA[SWZ(tid + (e << 8))] = make_float2(z[e].r, z[e].i);
    __syncthreads();

    float2* Po = (float2*)(P + (size_t)token * CCH);
    for (int bin = tid; bin < NBINS; bin += 256) {
        float2 Zb = bA[SWZ(bin)];
        float2 Zm = bA[SWZ((1024 - bin) & 1023)];
        float ar = 0.5f * (Zb.x + Zm.x);
        float ai = 0.5f * (Zb.y - Zm.y);
        float br = 0.5f * (Zb.y + Zm.y);
        float bi = 0.5f * (Zm.x - Zb.x);
        Po[bin] = make_float2(ar * br - ai * bi, ar * bi + ai * br);
    }
}

// ---------------------------------------------------------------------------
// Cumsum pass 1: in-place local cumsum within each t-chunk + chunk totals.
// ---------------------------------------------------------------------------
__global__ __launch_bounds__(256) void cumsum_local(
        float* __restrict__ S, float* __restrict__ totals) {
    const int c = blockIdx.x * 256 + threadIdx.x;
    if (c >= CCH) return;
    const int chunk = blockIdx.y;
    const int b = blockIdx.z;
    size_t p = ((size_t)b * L_SZ + (size_t)chunk * TLEN) * CCH + c;
    float acc = 0.0f;
    #pragma unroll 4
    for (int t = 0; t < TLEN; t++) {
        acc += S[p];
        S[p] = acc;
        p += CCH;
    }
    totals[((size_t)b * TCH + chunk) * CCH + c] = acc;
}

// Pass 2: turn chunk totals into EXCLUSIVE prefix offsets (in place).
__global__ __launch_bounds__(256) void scan_totals(float* __restrict__ totals) {
    const int c = blockIdx.x * 256 + threadIdx.x;
    if (c >= CCH) return;
    const int b = blockIdx.y;
    float acc = 0.0f;
    for (int ch = 0; ch < TCH; ch++) {
        size_t idx = ((size_t)b * TCH + ch) * CCH + c;
        float v = totals[idx];
        totals[idx] = acc;
        acc += v;
    }
}

// ---------------------------------------------------------------------------
// Unbind: recompute normalized-key FFT, Rf = (S_local+off)*conj(Kf),
// Hermitian extend, inverse FFT, /sqrt(t+1), LayerNorm -> bf16 RLN.
// ---------------------------------------------------------------------------
__global__ __launch_bounds__(256) void unbind_ln_kernel(
        const float* __restrict__ P, const float* __restrict__ totals,
        const float* __restrict__ Kraw,
        const float* __restrict__ ln_g, const float* __restrict__ ln_b,
        unsigned short* __restrict__ RLNb) {
    __shared__ float2 bA[1024], bB[1024];
    __shared__ float red1[256], red2[256];
    const int token = blockIdx.x;
    const int tid = threadIdx.x;
    const int b = token >> 12;
    const int t = token & (L_SZ - 1);
    const int chunk = t >> 7;

    const float* krow = Kraw + (size_t)token * D_SZ;
    float kv[4];
    float ss = 0.0f;
    #pragma unroll
    for (int k = 0; k < 4; k++) {
        kv[k] = krow[tid + (k << 8)];
        ss += kv[k] * kv[k];
    }
    red1[tid] = ss;
    __syncthreads();
    for (int sft = 128; sft > 0; sft >>= 1) {
        if (tid < sft) red1[tid] += red1[tid + sft];
        __syncthreads();
    }
    const float scale = 1.0f / fmaxf(sqrtf(red1[0]), 1e-12f);

    cplx kz[4];
    #pragma unroll
    for (int k = 0; k < 4; k++) kz[k] = {kv[k] * scale, 0.0f};

    __syncthreads();
    fft1024_r<-1>(bA, bB, kz, tid);     // kz[e] = Kf[tid + 256e]

    const float2* Srow   = (const float2*)(P + (size_t)token * CCH);
    const float2* offrow = (const float2*)(totals + ((size_t)b * TCH + chunk) * CCH);
    #pragma unroll
    for (int e = 0; e < 3; e++) {
        const int bin = tid + (e << 8);
        if (bin < NBINS) {
            float2 s2 = Srow[bin];
            float2 o2 = offrow[bin];
            float sr = s2.x + o2.x, si = s2.y + o2.y;
            float kr = kz[e].r, ki = kz[e].i;
            bA[SWZ(bin)] = make_float2(sr * kr + si * ki, si * kr - sr * ki);
        }
    }
    __syncthreads();
    for (int n = 513 + tid; n < 1024; n += 256) {
        float2 c = bA[SWZ(1024 - n)];
        bA[SWZ(n)] = make_float2(c.x, -c.y);
    }
    __syncthreads();

    cplx rz[4];
    #pragma unroll
    for (int k = 0; k < 4; k++) {
        float2 c = bA[SWZ(tid + (k << 8))];
        rz[k] = {c.x, c.y};
    }
    __syncthreads();
    fft1024_r<1>(bA, bB, rz, tid);      // rz[e].r = r[tid + 256e] * 1024

    const float posscale = (1.0f / 1024.0f) * rsqrtf((float)(t + 1));
    float rv[4];
    float sum = 0.0f, sumsq = 0.0f;
    #pragma unroll
    for (int e = 0; e < 4; e++) {
        float v = rz[e].r * posscale;
        rv[e] = v;
        sum += v;
        sumsq += v * v;
    }
    red1[tid] = sum; red2[tid] = sumsq;
    __syncthreads();
    for (int sft = 128; sft > 0; sft >>= 1) {
        if (tid < sft) { red1[tid] += red1[tid + sft]; red2[tid] += red2[tid + sft]; }
        __syncthreads();
    }
    const float mu = red1[0] * (1.0f / 1024.0f);
    const float var = red2[0] * (1.0f / 1024.0f) - mu * mu;
    const float rstd = rsqrtf(var + 1e-5f);

    unsigned short* outp = RLNb + (size_t)token * D_SZ;
    #pragma unroll
    for (int e = 0; e < 4; e++) {
        const int d = tid + (e << 8);
        outp[d] = f2bf((rv[e] - mu) * rstd * ln_g[d] + ln_b[d]);
    }
}

// ---------------------------------------------------------------------------
// Workspace (bytes):
//   Kraw   fp32 M*D    = 64.0 MB
//   V      fp32 M*D    = 64.0 MB  (dead after bind; reused as bf16 RLN)
//   P      fp32 M*CCH  = 67.2 MB  (local cumsum in place)
//   totals fp32        =  0.5 MB
//   xb     bf16 M*D    = 32.0 MB
//   WB     bf16 2048*D =  4.0 MB  (Wk ++ Wv, concatenated)
//   Wob    bf16 D*D    =  2.0 MB
//   total ~= 234 MB
// ---------------------------------------------------------------------------
extern "C" void kernel_launch(void* const* d_in, const int* in_sizes, int n_in,
                              void* d_out, int out_size, void* d_ws, size_t ws_size,
                              hipStream_t stream) {
    (void)in_sizes; (void)n_in; (void)out_size; (void)ws_size;
    const float* x    = (const float*)d_in[0];
    const float* Wk   = (const float*)d_in[1];
    const float* bk   = (const float*)d_in[2];
    const float* Wv   = (const float*)d_in[3];
    const float* bv   = (const float*)d_in[4];
    const float* ln_g = (const float*)d_in[5];
    const float* ln_b = (const float*)d_in[6];
    const float* Wo   = (const float*)d_in[7];
    const float* bo   = (const float*)d_in[8];
    float* out = (float*)d_out;

    char* w = (char*)d_ws;
    float* Kraw   = (float*)w;  w += (size_t)M_SZ * D_SZ * 4;
    float* V      = (float*)w;  w += (size_t)M_SZ * D_SZ * 4;
    float* P      = (float*)w;  w += (size_t)M_SZ * CCH * 4;
    float* totals = (float*)w;  w += (size_t)B_SZ * TCH * CCH * 4;
    unsigned short* xb  = (unsigned short*)w;  w += (size_t)M_SZ * D_SZ * 2;
    unsigned short* WB  = (unsigned short*)w;  w += (size_t)2 * D_SZ * D_SZ * 2;
    unsigned short* Wob = (unsigned short*)w;  w += (size_t)D_SZ * D_SZ * 2;
    unsigned short* RLNb = (unsigned short*)V;  // overlays dead V

    const int n8x = M_SZ * D_SZ / 8;
    const int n8w = D_SZ * D_SZ / 8;
    cast_f32_bf16<<<n8x / 256, 256, 0, stream>>>(x,  xb,  n8x);
    cast_f32_bf16<<<n8w / 256, 256, 0, stream>>>(Wk, WB,                  n8w);
    cast_f32_bf16<<<n8w / 256, 256, 0, stream>>>(Wv, WB + D_SZ * D_SZ,    n8w);
    cast_f32_bf16<<<n8w / 256, 256, 0, stream>>>(Wo, Wob, n8w);

    // fused K/V projection: N=2048 (first half -> Kraw, second -> V)
    gemm_mfma<16><<<(M_SZ / GBM) * 16, 256, 0, stream>>>(
        xb, WB, bk, bv, nullptr, Kraw, V, M_SZ, D_SZ);

    bind_fft_kernel<<<M_SZ, 256, 0, stream>>>(Kraw, V, P);

    dim3 cgrid((CCH + 255) / 256, TCH, B_SZ);
    cumsum_local<<<cgrid, 256, 0, stream>>>(P, totals);
    dim3 sgrid((CCH + 255) / 256, B_SZ);
    scan_totals<<<sgrid, 256, 0, stream>>>(totals);

    unbind_ln_kernel<<<M_SZ, 256, 0, stream>>>(P, totals, Kraw, ln_g, ln_b, RLNb);

    // output GEMM with fp32 residual
    gemm_mfma<8><<<(M_SZ / GBM) * 8, 256, 0, stream>>>(
        RLNb, Wob, bo, bo, x, out, out, M_SZ, D_SZ);
}